// Round 5
// baseline (1901.427 us; speedup 1.0000x reference)
//
#include <hip/hip_runtime.h>

// EncoderGRUODE: B=256, T=512, D_IN=64, H=128
// R5 = R4 core minus the writer-thread input pipeline (bisect: R4 failed at
// absmax 8.5e-2; R1-R3 with inline input select all passed).
// 1024 thr/block (16 waves, 4/EU). One 8-lane octet per hidden row.
// Per-thread weights 88 floats -> fits the 128-VGPR envelope the allocator
// always grants (R1-R3 evidence). W_out in LDS (42 KB). h-vectors swizzled
// (HSTRIDE=20): the 8 octet b128 windows cover all 32 banks disjointly.
// scan8 = 3 DPP row_shr adds; owners are lanes 7/15 of each 16-lane DPP row,
// whose prefix sums never cross the octet boundary.
// Input staging: sh_x parity buffer, filled by 64 threads inside step s for
// step s+1 (write pre-B4, read post-B4 of s+1); GRU selects sh_x vs sh_po
// by the uniform mask bit (R3-proven semantics).

#define NB    256
#define TB    1024
#define TSTEP 512
#define DIN   64
#define HD    128

#define HSTRIDE 20
#define HSZ     160
#define WOSTRIDE 164

typedef float v2f __attribute__((ext_vector_type(2)));

__device__ __forceinline__ float fast_tanh(float v) {
    float e = __expf(2.0f * v);
    return 1.0f - 2.0f / (e + 1.0f);
}
__device__ __forceinline__ float fast_sigmoid(float v) {
    return 1.0f / (1.0f + __expf(-v));
}

template<int CTRL>
__device__ __forceinline__ float dpp_add(float v) {
    return v + __int_as_float(__builtin_amdgcn_update_dpp(
        0, __float_as_int(v), CTRL, 0xF, 0xF, true));
}
// 8-lane inclusive reduction; lanes 7/15 of each DPP row hold their octet's total.
__device__ __forceinline__ float scan8(float v) {
    v = dpp_add<0x111>(v);  // row_shr:1
    v = dpp_add<0x112>(v);  // row_shr:2
    v = dpp_add<0x114>(v);  // row_shr:4
    return v;
}

__global__ __launch_bounds__(TB) __attribute__((amdgpu_waves_per_eu(4, 4)))
void gruode_kernel(
    const float* __restrict__ x,         // [B, T, DIN]
    const float* __restrict__ tp,        // [B, T] (row 0 used)
    const int*   __restrict__ samp_mask, // [T]
    const float* __restrict__ W_ih,      // [3H, DIN]
    const float* __restrict__ W_hh,      // [3H, H]
    const float* __restrict__ b_ih,      // [3H]
    const float* __restrict__ b_hh,      // [3H]
    const float* __restrict__ W_node,    // [H, H]
    const float* __restrict__ b_node,    // [H]
    const float* __restrict__ W_out,     // [DIN, H]
    const float* __restrict__ b_out,     // [DIN]
    float*       __restrict__ out)       // [B*T, DIN]
{
    const int t     = threadIdx.x;
    const int b     = blockIdx.x;
    const int g     = t >> 3;        // octet id = hidden row 0..127
    const int kkk   = t & 7;         // k-lane within octet
    const bool owner = (kkk == 7);
    const int gsw   = HSTRIDE * (g >> 4) + (g & 15);   // swizzled slot of row g

    __shared__ __align__(16) float sh_h [HSZ];
    __shared__ __align__(16) float sh_t0[HSZ];
    __shared__ __align__(16) float sh_t1[HSZ];
    __shared__ __align__(16) float sh_x [2][DIN];
    __shared__ __align__(16) float sh_po[DIN];
    __shared__ __align__(16) float sh_wout[DIN * WOSTRIDE];  // 42 KB

    const float4* Wn4  = (const float4*)W_node;  // [128][32 f4]
    const float4* Whh4 = (const float4*)W_hh;    // [384][32 f4]
    const float4* Wih4 = (const float4*)W_ih;    // [384][16 f4]
    const float4* Wo4  = (const float4*)W_out;   // [64][32 f4]

    // ---- weights -> registers: 88 floats/thread ----
    v2f Wn[8], Whr[8], Whz[8], Whn[8];
    #pragma unroll
    for (int u = 0; u < 4; ++u) {
        float4 w;
        w = Wn4[g*32 + kkk*4 + u];
        Wn [2*u] = (v2f){w.x, w.y}; Wn [2*u+1] = (v2f){w.z, w.w};
        w = Whh4[(0*HD + g)*32 + kkk*4 + u];
        Whr[2*u] = (v2f){w.x, w.y}; Whr[2*u+1] = (v2f){w.z, w.w};
        w = Whh4[(1*HD + g)*32 + kkk*4 + u];
        Whz[2*u] = (v2f){w.x, w.y}; Whz[2*u+1] = (v2f){w.z, w.w};
        w = Whh4[(2*HD + g)*32 + kkk*4 + u];
        Whn[2*u] = (v2f){w.x, w.y}; Whn[2*u+1] = (v2f){w.z, w.w};
    }
    v2f Wir[4], Wiz[4], Win[4];
    #pragma unroll
    for (int u = 0; u < 2; ++u) {
        float4 w;
        w = Wih4[(0*HD + g)*16 + kkk*2 + u];
        Wir[2*u] = (v2f){w.x, w.y}; Wir[2*u+1] = (v2f){w.z, w.w};
        w = Wih4[(1*HD + g)*16 + kkk*2 + u];
        Wiz[2*u] = (v2f){w.x, w.y}; Wiz[2*u+1] = (v2f){w.z, w.w};
        w = Wih4[(2*HD + g)*16 + kkk*2 + u];
        Win[2*u] = (v2f){w.x, w.y}; Win[2*u+1] = (v2f){w.z, w.w};
    }
    // pin against rematerialization/sinking into the loop
    #pragma unroll
    for (int i = 0; i < 8; ++i) {
        asm volatile("" : "+v"(Wn[i]));  asm volatile("" : "+v"(Whr[i]));
        asm volatile("" : "+v"(Whz[i])); asm volatile("" : "+v"(Whn[i]));
    }
    #pragma unroll
    for (int i = 0; i < 4; ++i) {
        asm volatile("" : "+v"(Wir[i])); asm volatile("" : "+v"(Wiz[i]));
        asm volatile("" : "+v"(Win[i]));
    }

    // per-row biases (consumed on owner lane)
    const float bn  = b_node[g];
    const float br  = b_ih[0*HD + g] + b_hh[0*HD + g];
    const float bz  = b_ih[1*HD + g] + b_hh[1*HD + g];
    const float bin = b_ih[2*HD + g];
    const float bhn = b_hh[2*HD + g];
    const float bo  = (g < DIN) ? b_out[g] : 0.0f;

    // ---- LDS init ----
    if (t < HD)  sh_h[HSTRIDE*(t>>4) + (t&15)] = 0.0f;      // h0 = 0
    if (t < DIN) sh_po[t] = b_out[t];                       // prev_out(h0)
    if (t < DIN) sh_x[0][t] = x[(size_t)b * TSTEP * DIN + t];
    if (t < 512) {  // W_out -> LDS, swizzled rows
        const int gg = t >> 3, k2 = t & 7;
        #pragma unroll
        for (int u = 0; u < 4; ++u) {
            float4 w = Wo4[gg*32 + k2*4 + u];
            *(float4*)(sh_wout + gg*WOSTRIDE + k2*HSTRIDE + 4*u) = w;
        }
    }
    __syncthreads();

    const int bufoff = HSTRIDE * kkk;

    // octet-sliced dot over a swizzled 128-float LDS vector (16 MACs)
    auto dot16 = [&](const v2f (&w)[8], const float* buf) -> float {
        const float4* p = (const float4*)(buf + bufoff);
        v2f a0 = {0.f, 0.f}, a1 = {0.f, 0.f};
        #pragma unroll
        for (int u = 0; u < 4; ++u) {
            float4 v = p[u];
            a0 = w[2*u]   * (v2f){v.x, v.y} + a0;
            a1 = w[2*u+1] * (v2f){v.z, v.w} + a1;
        }
        v2f a = a0 + a1;
        return a.x + a.y;
    };

    float hj = 0.0f;                   // owner lanes: h[g]
    float tp_prev = tp[0] - 0.01f;     // dts[0] = 0.01

    #pragma unroll 1
    for (int s = 0; s < TSTEP; ++s) {
        // uniform per-step scalars (issued early, consumed after latency)
        const float tpv   = tp[s];
        const int   m_cur = samp_mask[s];
        const float dt    = tpv - tp_prev;
        tp_prev = tpv;

        // prefetch x row for step s+1 (consumed pre-B4; ~3 RK4 stages of slack)
        const int sn = (s + 1 < TSTEP) ? s + 1 : s;
        float xn = 0.0f;
        if (t < DIN) xn = x[((size_t)b * TSTEP + sn) * DIN + t];

        // ---- RK4 on dh/dt = tanh(Wn h + bn) ----
        float k1 = fast_tanh(scan8(dot16(Wn, sh_h)) + bn);
        if (owner) sh_t0[gsw] = fmaf(0.5f*dt, k1, hj);
        __syncthreads();                                   // B1

        float k2 = fast_tanh(scan8(dot16(Wn, sh_t0)) + bn);
        if (owner) sh_t1[gsw] = fmaf(0.5f*dt, k2, hj);
        __syncthreads();                                   // B2

        float k3 = fast_tanh(scan8(dot16(Wn, sh_t1)) + bn);
        if (owner) sh_t0[gsw] = fmaf(dt, k3, hj);
        __syncthreads();                                   // B3

        float k4 = fast_tanh(scan8(dot16(Wn, sh_t0)) + bn);
        const float hode = fmaf(dt * (1.0f/6.0f),
                                (k1 + 2.0f*k2) + (2.0f*k3 + k4), hj);
        if (owner) sh_t1[gsw] = hode;                      // t1 = h_ode vector
        if (t < DIN) sh_x[(s + 1) & 1][t] = xn;            // stage next input
        __syncthreads();                                   // B4

        // ---- GRU cell: hidden from t1 (h_ode); input = mask ? x_s : prev_out
        {
            const float* insrc = m_cur ? sh_x[s & 1] : sh_po;
            const float4* pi = (const float4*)(insrc + 8*kkk);
            const float4* ph = (const float4*)(sh_t1 + bufoff);

            v2f sR = {0.f,0.f}, sZ = {0.f,0.f}, sH = {0.f,0.f}, sI = {0.f,0.f};
            // hidden halves (keeps live h-regs at 8)
            {
                float4 va = ph[0], vb = ph[1];
                v2f h0={va.x,va.y}, h1={va.z,va.w}, h2={vb.x,vb.y}, h3={vb.z,vb.w};
                sR = Whr[0]*h0+sR; sR = Whr[1]*h1+sR; sR = Whr[2]*h2+sR; sR = Whr[3]*h3+sR;
                sZ = Whz[0]*h0+sZ; sZ = Whz[1]*h1+sZ; sZ = Whz[2]*h2+sZ; sZ = Whz[3]*h3+sZ;
                sH = Whn[0]*h0+sH; sH = Whn[1]*h1+sH; sH = Whn[2]*h2+sH; sH = Whn[3]*h3+sH;
            }
            {
                float4 vc = ph[2], vd = ph[3];
                v2f h4={vc.x,vc.y}, h5={vc.z,vc.w}, h6={vd.x,vd.y}, h7={vd.z,vd.w};
                sR = Whr[4]*h4+sR; sR = Whr[5]*h5+sR; sR = Whr[6]*h6+sR; sR = Whr[7]*h7+sR;
                sZ = Whz[4]*h4+sZ; sZ = Whz[5]*h5+sZ; sZ = Whz[6]*h6+sZ; sZ = Whz[7]*h7+sZ;
                sH = Whn[4]*h4+sH; sH = Whn[5]*h5+sH; sH = Whn[6]*h6+sH; sH = Whn[7]*h7+sH;
            }
            {
                float4 w0 = pi[0], w1 = pi[1];
                v2f i0={w0.x,w0.y}, i1={w0.z,w0.w}, i2={w1.x,w1.y}, i3={w1.z,w1.w};
                sR = Wir[0]*i0+sR; sR = Wir[1]*i1+sR; sR = Wir[2]*i2+sR; sR = Wir[3]*i3+sR;
                sZ = Wiz[0]*i0+sZ; sZ = Wiz[1]*i1+sZ; sZ = Wiz[2]*i2+sZ; sZ = Wiz[3]*i3+sZ;
                sI = Win[0]*i0+sI; sI = Win[1]*i1+sI; sI = Win[2]*i2+sI; sI = Win[3]*i3+sI;
            }

            float R  = scan8(sR.x + sR.y);
            float Z  = scan8(sZ.x + sZ.y);
            float Nh = scan8(sH.x + sH.y);
            float Ni = scan8(sI.x + sI.y);

            float rr = fast_sigmoid(R + br);
            float zz = fast_sigmoid(Z + bz);
            float nn = fast_tanh(fmaf(rr, Nh + bhn, Ni + bin));
            float hnew = fmaf(zz, hode - nn, nn);          // (1-z)n + z*h_ode
            hj = hnew;
            if (owner) sh_h[gsw] = hnew;
        }
        __syncthreads();                                   // B5

        // ---- out_t = h_new @ W_out^T + b_out (waves 0-7) ----
        if (g < DIN) {
            const float4* pw = (const float4*)(sh_wout + g*WOSTRIDE + bufoff);
            const float4* ph = (const float4*)(sh_h + bufoff);
            v2f a0 = {0.f,0.f}, a1 = {0.f,0.f};
            #pragma unroll
            for (int u = 0; u < 4; ++u) {
                float4 wv = pw[u];
                float4 hv = ph[u];
                a0 = (v2f){wv.x,wv.y} * (v2f){hv.x,hv.y} + a0;
                a1 = (v2f){wv.z,wv.w} * (v2f){hv.z,hv.w} + a1;
            }
            v2f a = a0 + a1;
            float o = scan8(a.x + a.y);
            if (owner) {
                float oo = o + bo;
                sh_po[g] = oo;
                out[((size_t)b * TSTEP + s) * DIN + g] = oo;
            }
        }
        __syncthreads();                                   // B6
    }
}

extern "C" void kernel_launch(void* const* d_in, const int* in_sizes, int n_in,
                              void* d_out, int out_size, void* d_ws, size_t ws_size,
                              hipStream_t stream) {
    (void)in_sizes; (void)n_in; (void)d_ws; (void)ws_size; (void)out_size;
    const float* x      = (const float*)d_in[0];
    const float* tp     = (const float*)d_in[1];
    const int*   mask   = (const int*)  d_in[2];
    const float* W_ih   = (const float*)d_in[3];
    const float* W_hh   = (const float*)d_in[4];
    const float* b_ih   = (const float*)d_in[5];
    const float* b_hh   = (const float*)d_in[6];
    const float* W_node = (const float*)d_in[7];
    const float* b_node = (const float*)d_in[8];
    const float* W_out  = (const float*)d_in[9];
    const float* b_out  = (const float*)d_in[10];
    float* outp = (float*)d_out;

    gruode_kernel<<<NB, TB, 0, stream>>>(x, tp, mask, W_ih, W_hh, b_ih, b_hh,
                                         W_node, b_node, W_out, b_out, outp);
}

// Round 6
// 1529.697 us; speedup vs baseline: 1.2430x; 1.2430x over previous
//
#include <hip/hip_runtime.h>

// EncoderGRUODE: B=256, T=512, D_IN=64, H=128
// R6: the LDS-pipe theory round. All rounds R1-R5 were bound by broadcast-
// amplified h-vector LDS reads (volume = threads*128/q; ds_read_b128 ~12cy/CU).
// Fix: q=16 lanes/row, r=4 rows/thread at 512 threads -> ~13 b128/thread/step.
// h stored at stride 12 floats per 8 (lane kk slice at 48kk B -> 2-way max
// bank aliasing = free; R3's 32B-stride caused 4.2e7 4-way conflicts).
// Weights fully register-resident by construction: Wn (used 4x/step) in VGPR,
// Whh/Wih/Wo (1x/step, 160 fl) pinned to AGPR ("+a"); gfx950 VALU reads AGPR
// srcs directly. V~90 + A~160 = 250 <= 256 @ 2 waves/SIMD (waves_per_eu(2,2)).
// Reductions: DPP scan16 (row_shr 1,2,4,8) + quad_perm(3,3,3,3) + rsel select;
// owner lanes 12..15 of each 16-lane group hold rows 4g+0..3 (R3-proven).
// Input staging: R5's parity-buffered sh_x (passed correctness).

#define NB    256
#define TB    512
#define TSTEP 512
#define DIN   64
#define HD    128

// swizzled h layout: float j at slot 12*(j>>3) + (j&7); 16 slices -> 192 slots
#define HSZ 192

typedef float v2f __attribute__((ext_vector_type(2)));

__device__ __forceinline__ float fast_tanh(float v) {
    float e = __expf(2.0f * v);
    return 1.0f - 2.0f / (e + 1.0f);
}
__device__ __forceinline__ float fast_sigmoid(float v) {
    return 1.0f / (1.0f + __expf(-v));
}

template<int CTRL>
__device__ __forceinline__ float dpp_add(float v) {
    return v + __int_as_float(__builtin_amdgcn_update_dpp(
        0, __float_as_int(v), CTRL, 0xF, 0xF, true));
}
// inclusive prefix over each 16-lane DPP row; lane 15 holds the row total
__device__ __forceinline__ float scan16(float v) {
    v = dpp_add<0x111>(v);  // row_shr:1
    v = dpp_add<0x112>(v);  // row_shr:2
    v = dpp_add<0x114>(v);  // row_shr:4
    v = dpp_add<0x118>(v);  // row_shr:8
    return v;
}
// quad_perm [3,3,3,3]: lanes 12..15 receive lane 15's value (= scan16 total)
__device__ __forceinline__ float qp3333(float v) {
    return __int_as_float(__builtin_amdgcn_update_dpp(
        0, __float_as_int(v), 0xFF, 0xF, 0xF, true));
}

__global__ __launch_bounds__(TB) __attribute__((amdgpu_waves_per_eu(2, 2)))
void gruode_kernel(
    const float* __restrict__ x,         // [B, T, DIN]
    const float* __restrict__ tp,        // [B, T] (row 0 used)
    const int*   __restrict__ samp_mask, // [T]
    const float* __restrict__ W_ih,      // [3H, DIN]
    const float* __restrict__ W_hh,      // [3H, H]
    const float* __restrict__ b_ih,      // [3H]
    const float* __restrict__ b_hh,      // [3H]
    const float* __restrict__ W_node,    // [H, H]
    const float* __restrict__ b_node,    // [H]
    const float* __restrict__ W_out,     // [DIN, H]
    const float* __restrict__ b_out,     // [DIN]
    float*       __restrict__ out)       // [B*T, DIN]
{
    const int t    = threadIdx.x;    // 0..511
    const int b    = blockIdx.x;
    const int g    = t >> 4;         // group 0..31: hidden rows 4g..4g+3, out rows 2g..2g+1
    const int kk   = t & 15;         // k-lane: h-slice floats 8kk..8kk+7, in-slice 4kk..4kk+3
    const int rsel = kk & 3;         // owner lanes 12..15 hold row 4g+rsel
    const bool own4 = (kk >= 12);
    // swizzled write slot for row 4g+rsel: 12*((4g+rsel)>>3) + ((4g+rsel)&7)
    const int gsw  = 12 * (g >> 1) + 4 * (g & 1);   // + rsel at use site

    __shared__ __align__(16) float sh_h [HSZ];
    __shared__ __align__(16) float sh_t0[HSZ];
    __shared__ __align__(16) float sh_t1[HSZ];
    __shared__ __align__(16) float sh_x [2][DIN];
    __shared__ __align__(16) float sh_po[DIN];

    const float4* Wn4  = (const float4*)W_node;  // [128][32 f4]
    const float4* Whh4 = (const float4*)W_hh;    // [384][32 f4]
    const float4* Wih4 = (const float4*)W_ih;    // [384][16 f4]
    const float4* Wo4  = (const float4*)W_out;   // [64][32 f4]

    // ---- weights -> registers ----
    // Wn: 4 rows x 8 floats = 32 fl (VGPR, used 4x/step)
    v2f Wn[4][4];
    // Whh gates: 4 rows x 8 fl x 3 = 96 fl (AGPR)
    v2f Whr[4][4], Whz[4][4], Whn[4][4];
    // Wih gates: 4 rows x 4 fl x 3 = 48 fl (AGPR)
    v2f Wir[4][2], Wiz[4][2], Win[4][2];
    // Wo: 2 rows x 8 fl = 16 fl (AGPR)
    v2f Wo[2][4];

    #pragma unroll
    for (int r = 0; r < 4; ++r) {
        const int row = 4*g + r;
        float4 a, c;
        a = Wn4[row*32 + 2*kk]; c = Wn4[row*32 + 2*kk + 1];
        Wn[r][0]=(v2f){a.x,a.y}; Wn[r][1]=(v2f){a.z,a.w};
        Wn[r][2]=(v2f){c.x,c.y}; Wn[r][3]=(v2f){c.z,c.w};
        a = Whh4[(0*HD+row)*32 + 2*kk]; c = Whh4[(0*HD+row)*32 + 2*kk + 1];
        Whr[r][0]=(v2f){a.x,a.y}; Whr[r][1]=(v2f){a.z,a.w};
        Whr[r][2]=(v2f){c.x,c.y}; Whr[r][3]=(v2f){c.z,c.w};
        a = Whh4[(1*HD+row)*32 + 2*kk]; c = Whh4[(1*HD+row)*32 + 2*kk + 1];
        Whz[r][0]=(v2f){a.x,a.y}; Whz[r][1]=(v2f){a.z,a.w};
        Whz[r][2]=(v2f){c.x,c.y}; Whz[r][3]=(v2f){c.z,c.w};
        a = Whh4[(2*HD+row)*32 + 2*kk]; c = Whh4[(2*HD+row)*32 + 2*kk + 1];
        Whn[r][0]=(v2f){a.x,a.y}; Whn[r][1]=(v2f){a.z,a.w};
        Whn[r][2]=(v2f){c.x,c.y}; Whn[r][3]=(v2f){c.z,c.w};
        a = Wih4[(0*HD+row)*16 + kk];
        Wir[r][0]=(v2f){a.x,a.y}; Wir[r][1]=(v2f){a.z,a.w};
        a = Wih4[(1*HD+row)*16 + kk];
        Wiz[r][0]=(v2f){a.x,a.y}; Wiz[r][1]=(v2f){a.z,a.w};
        a = Wih4[(2*HD+row)*16 + kk];
        Win[r][0]=(v2f){a.x,a.y}; Win[r][1]=(v2f){a.z,a.w};
    }
    #pragma unroll
    for (int r = 0; r < 2; ++r) {
        const int row = 2*g + r;
        float4 a = Wo4[row*32 + 2*kk], c = Wo4[row*32 + 2*kk + 1];
        Wo[r][0]=(v2f){a.x,a.y}; Wo[r][1]=(v2f){a.z,a.w};
        Wo[r][2]=(v2f){c.x,c.y}; Wo[r][3]=(v2f){c.z,c.w};
    }
    // Pin: Wn in VGPRs (hot), the rest in AGPRs (gfx950 VALU reads AGPR srcs)
    #pragma unroll
    for (int r = 0; r < 4; ++r) {
        #pragma unroll
        for (int i = 0; i < 4; ++i) {
            asm volatile("" : "+v"(Wn[r][i]));
            asm volatile("" : "+a"(Whr[r][i]));
            asm volatile("" : "+a"(Whz[r][i]));
            asm volatile("" : "+a"(Whn[r][i]));
        }
        #pragma unroll
        for (int i = 0; i < 2; ++i) {
            asm volatile("" : "+a"(Wir[r][i]));
            asm volatile("" : "+a"(Wiz[r][i]));
            asm volatile("" : "+a"(Win[r][i]));
        }
    }
    #pragma unroll
    for (int i = 0; i < 4; ++i) {
        asm volatile("" : "+a"(Wo[0][i]));
        asm volatile("" : "+a"(Wo[1][i]));
    }

    // per-lane biases for the row this lane owns after regroup
    const int rl = 4*g + rsel;
    const float bn  = b_node[rl];
    const float br  = b_ih[0*HD + rl] + b_hh[0*HD + rl];
    const float bz  = b_ih[1*HD + rl] + b_hh[1*HD + rl];
    const float bin = b_ih[2*HD + rl];
    const float bhn = b_hh[2*HD + rl];
    const float bo  = b_out[2*g + (kk & 1)];

    // ---- LDS init ----
    if (t < HSZ) sh_h[t] = 0.0f;                       // h0 = 0 (incl. pads)
    if (t < DIN) sh_po[t] = b_out[t];                  // prev_out(h0) = b_out
    if (t < DIN) sh_x[0][t] = x[(size_t)b * TSTEP * DIN + t];
    __syncthreads();

    const int soff = 12 * kk;   // this lane's swizzled slice base (floats)

    // 4-row partial dot over a swizzled 128-float LDS vector (thread k-slice)
    auto dotWn = [&](const float* buf, float (&acc)[4]) {
        const float4* p = (const float4*)(buf + soff);
        float4 a = p[0], c = p[1];
        v2f x0={a.x,a.y}, x1={a.z,a.w}, x2={c.x,c.y}, x3={c.z,c.w};
        #pragma unroll
        for (int r = 0; r < 4; ++r) {
            v2f s = Wn[r][0]*x0;
            s = Wn[r][1]*x1 + s; s = Wn[r][2]*x2 + s; s = Wn[r][3]*x3 + s;
            acc[r] = s.x + s.y;
        }
    };
    // reduce 4 row-partials over 16 lanes; lanes 12..15 get row 4g+rsel's total
    auto reduce4 = [&](const float (&acc)[4]) -> float {
        float s0 = qp3333(scan16(acc[0]));
        float s1 = qp3333(scan16(acc[1]));
        float s2 = qp3333(scan16(acc[2]));
        float s3 = qp3333(scan16(acc[3]));
        float lo = (rsel & 1) ? s1 : s0;
        float hi = (rsel & 1) ? s3 : s2;
        return (rsel & 2) ? hi : lo;
    };

    float hj = 0.0f;                  // owner lanes: h[4g+rsel]
    float tp_prev = tp[0] - 0.01f;    // dts[0] = 0.01

    #pragma unroll 1
    for (int s = 0; s < TSTEP; ++s) {
        const float tpv   = tp[s];
        const int   m_cur = samp_mask[s];
        const float dt    = tpv - tp_prev;
        tp_prev = tpv;

        // prefetch x row for step s+1 (consumed pre-B4)
        const int sn = (s + 1 < TSTEP) ? s + 1 : s;
        float xn = 0.0f;
        if (t < DIN) xn = x[((size_t)b * TSTEP + sn) * DIN + t];

        float acc[4];

        // ---- RK4 on dh/dt = tanh(Wn h + bn) ----
        dotWn(sh_h, acc);
        float k1 = fast_tanh(reduce4(acc) + bn);
        if (own4) sh_t0[gsw + rsel] = fmaf(0.5f*dt, k1, hj);
        __syncthreads();                                   // B1

        dotWn(sh_t0, acc);
        float k2 = fast_tanh(reduce4(acc) + bn);
        if (own4) sh_t1[gsw + rsel] = fmaf(0.5f*dt, k2, hj);
        __syncthreads();                                   // B2

        dotWn(sh_t1, acc);
        float k3 = fast_tanh(reduce4(acc) + bn);
        if (own4) sh_t0[gsw + rsel] = fmaf(dt, k3, hj);
        __syncthreads();                                   // B3

        dotWn(sh_t0, acc);
        float k4 = fast_tanh(reduce4(acc) + bn);
        const float hode = fmaf(dt * (1.0f/6.0f),
                                (k1 + 2.0f*k2) + (2.0f*k3 + k4), hj);
        if (own4) sh_t1[gsw + rsel] = hode;                // t1 = h_ode vector
        if (t < DIN) sh_x[(s + 1) & 1][t] = xn;            // stage next input
        __syncthreads();                                   // B4

        // ---- GRU cell: hidden from t1 (h_ode); input = mask ? x_s : prev_out
        {
            const float4* ph = (const float4*)(sh_t1 + soff);
            float4 a = ph[0], c = ph[1];
            v2f h0={a.x,a.y}, h1={a.z,a.w}, h2={c.x,c.y}, h3={c.z,c.w};
            const float* insrc = m_cur ? sh_x[s & 1] : sh_po;
            float4 vi = *(const float4*)(insrc + 4*kk);
            v2f i0={vi.x,vi.y}, i1={vi.z,vi.w};

            float aR[4], aZ[4], aNh[4], aNi[4];
            #pragma unroll
            for (int r = 0; r < 4; ++r) {
                v2f sR = Whr[r][0]*h0;
                sR = Whr[r][1]*h1 + sR; sR = Whr[r][2]*h2 + sR; sR = Whr[r][3]*h3 + sR;
                sR = Wir[r][0]*i0 + sR; sR = Wir[r][1]*i1 + sR;
                aR[r] = sR.x + sR.y;
                v2f sZ = Whz[r][0]*h0;
                sZ = Whz[r][1]*h1 + sZ; sZ = Whz[r][2]*h2 + sZ; sZ = Whz[r][3]*h3 + sZ;
                sZ = Wiz[r][0]*i0 + sZ; sZ = Wiz[r][1]*i1 + sZ;
                aZ[r] = sZ.x + sZ.y;
                v2f sH = Whn[r][0]*h0;
                sH = Whn[r][1]*h1 + sH; sH = Whn[r][2]*h2 + sH; sH = Whn[r][3]*h3 + sH;
                aNh[r] = sH.x + sH.y;
                v2f sI = Win[r][0]*i0; sI = Win[r][1]*i1 + sI;
                aNi[r] = sI.x + sI.y;
            }
            float R  = reduce4(aR);
            float Z  = reduce4(aZ);
            float Nh = reduce4(aNh);
            float Ni = reduce4(aNi);

            float rr = fast_sigmoid(R + br);
            float zz = fast_sigmoid(Z + bz);
            float nn = fast_tanh(fmaf(rr, Nh + bhn, Ni + bin));
            float hnew = fmaf(zz, hode - nn, nn);          // (1-z)n + z*h_ode
            hj = hnew;
            if (own4) sh_h[gsw + rsel] = hnew;
        }
        __syncthreads();                                   // B5

        // ---- out_t = h_new @ W_out^T + b_out (rows 2g, 2g+1 per group) ----
        {
            const float4* ph = (const float4*)(sh_h + soff);
            float4 a = ph[0], c = ph[1];
            v2f x0={a.x,a.y}, x1={a.z,a.w}, x2={c.x,c.y}, x3={c.z,c.w};
            float o01[2];
            #pragma unroll
            for (int r = 0; r < 2; ++r) {
                v2f so = Wo[r][0]*x0;
                so = Wo[r][1]*x1 + so; so = Wo[r][2]*x2 + so; so = Wo[r][3]*x3 + so;
                o01[r] = so.x + so.y;
            }
            float so0 = qp3333(scan16(o01[0]));
            float so1 = qp3333(scan16(o01[1]));
            float o = ((kk & 1) ? so1 : so0) + bo;
            if (kk >= 14) {                    // lanes 14,15 -> rows 2g, 2g+1
                const int col = 2*g + (kk & 1);
                sh_po[col] = o;
                out[((size_t)b * TSTEP + s) * DIN + col] = o;
            }
        }
        __syncthreads();                                   // B6
    }
}

extern "C" void kernel_launch(void* const* d_in, const int* in_sizes, int n_in,
                              void* d_out, int out_size, void* d_ws, size_t ws_size,
                              hipStream_t stream) {
    (void)in_sizes; (void)n_in; (void)d_ws; (void)ws_size; (void)out_size;
    const float* x      = (const float*)d_in[0];
    const float* tp     = (const float*)d_in[1];
    const int*   mask   = (const int*)  d_in[2];
    const float* W_ih   = (const float*)d_in[3];
    const float* W_hh   = (const float*)d_in[4];
    const float* b_ih   = (const float*)d_in[5];
    const float* b_hh   = (const float*)d_in[6];
    const float* W_node = (const float*)d_in[7];
    const float* b_node = (const float*)d_in[8];
    const float* W_out  = (const float*)d_in[9];
    const float* b_out  = (const float*)d_in[10];
    float* outp = (float*)d_out;

    gruode_kernel<<<NB, TB, 0, stream>>>(x, tp, mask, W_ih, W_hh, b_ih, b_hh,
                                         W_node, b_node, W_out, b_out, outp);
}

// Round 7
// 1529.394 us; speedup vs baseline: 1.2433x; 1.0002x over previous
//
#include <hip/hip_runtime.h>

// EncoderGRUODE: B=256, T=512, D_IN=64, H=128
// R7 = R6 with the occupancy cap removed (single-variable change).
// R6 post-mortem: VALU-bound (74% busy) at 1.9 waves/SIMD because
// amdgpu_waves_per_eu(2,2) capped occupancy at ONE 8-wave block per CU.
// Unified-file math: 128 arch + ~166 acc ~ 294 regs/wave; 2048/SIMD file
// supports ~6 waves/SIMD -> 2-3 blocks/CU can co-reside and overlap each
// other's barriers. __launch_bounds__(512,2) is the R1/R2-proven combo that
// yields 128 arch VGPRs with no max-occupancy ceiling.
// Everything else identical to R6 (passed, absmax 1.95e-3, 0 bank conflicts):
// q=16 lanes/row, r=4 rows/thread; h swizzled at 12 floats per 8 (2-way max
// bank aliasing = free); Wn in VGPR, Whh/Wih/Wo pinned AGPR; DPP scan16 +
// quad_perm regroup reductions; parity-buffered sh_x input staging.

#define NB    256
#define TB    512
#define TSTEP 512
#define DIN   64
#define HD    128

// swizzled h layout: float j at slot 12*(j>>3) + (j&7); 16 slices -> 192 slots
#define HSZ 192

typedef float v2f __attribute__((ext_vector_type(2)));

__device__ __forceinline__ float fast_tanh(float v) {
    float e = __expf(2.0f * v);
    return 1.0f - 2.0f / (e + 1.0f);
}
__device__ __forceinline__ float fast_sigmoid(float v) {
    return 1.0f / (1.0f + __expf(-v));
}

template<int CTRL>
__device__ __forceinline__ float dpp_add(float v) {
    return v + __int_as_float(__builtin_amdgcn_update_dpp(
        0, __float_as_int(v), CTRL, 0xF, 0xF, true));
}
// inclusive prefix over each 16-lane DPP row; lane 15 holds the row total
__device__ __forceinline__ float scan16(float v) {
    v = dpp_add<0x111>(v);  // row_shr:1
    v = dpp_add<0x112>(v);  // row_shr:2
    v = dpp_add<0x114>(v);  // row_shr:4
    v = dpp_add<0x118>(v);  // row_shr:8
    return v;
}
// quad_perm [3,3,3,3]: lanes 12..15 receive lane 15's value (= scan16 total)
__device__ __forceinline__ float qp3333(float v) {
    return __int_as_float(__builtin_amdgcn_update_dpp(
        0, __float_as_int(v), 0xFF, 0xF, 0xF, true));
}

__global__ __launch_bounds__(TB, 2)
void gruode_kernel(
    const float* __restrict__ x,         // [B, T, DIN]
    const float* __restrict__ tp,        // [B, T] (row 0 used)
    const int*   __restrict__ samp_mask, // [T]
    const float* __restrict__ W_ih,      // [3H, DIN]
    const float* __restrict__ W_hh,      // [3H, H]
    const float* __restrict__ b_ih,      // [3H]
    const float* __restrict__ b_hh,      // [3H]
    const float* __restrict__ W_node,    // [H, H]
    const float* __restrict__ b_node,    // [H]
    const float* __restrict__ W_out,     // [DIN, H]
    const float* __restrict__ b_out,     // [DIN]
    float*       __restrict__ out)       // [B*T, DIN]
{
    const int t    = threadIdx.x;    // 0..511
    const int b    = blockIdx.x;
    const int g    = t >> 4;         // group 0..31: hidden rows 4g..4g+3, out rows 2g..2g+1
    const int kk   = t & 15;         // k-lane: h-slice floats 8kk..8kk+7, in-slice 4kk..4kk+3
    const int rsel = kk & 3;         // owner lanes 12..15 hold row 4g+rsel
    const bool own4 = (kk >= 12);
    // swizzled write slot for row 4g+rsel: 12*((4g+rsel)>>3) + ((4g+rsel)&7)
    const int gsw  = 12 * (g >> 1) + 4 * (g & 1);   // + rsel at use site

    __shared__ __align__(16) float sh_h [HSZ];
    __shared__ __align__(16) float sh_t0[HSZ];
    __shared__ __align__(16) float sh_t1[HSZ];
    __shared__ __align__(16) float sh_x [2][DIN];
    __shared__ __align__(16) float sh_po[DIN];

    const float4* Wn4  = (const float4*)W_node;  // [128][32 f4]
    const float4* Whh4 = (const float4*)W_hh;    // [384][32 f4]
    const float4* Wih4 = (const float4*)W_ih;    // [384][16 f4]
    const float4* Wo4  = (const float4*)W_out;   // [64][32 f4]

    // ---- weights -> registers ----
    v2f Wn[4][4];                            // 32 fl VGPR (hot, 4x/step)
    v2f Whr[4][4], Whz[4][4], Whn[4][4];     // 96 fl AGPR
    v2f Wir[4][2], Wiz[4][2], Win[4][2];     // 48 fl AGPR
    v2f Wo[2][4];                            // 16 fl AGPR

    #pragma unroll
    for (int r = 0; r < 4; ++r) {
        const int row = 4*g + r;
        float4 a, c;
        a = Wn4[row*32 + 2*kk]; c = Wn4[row*32 + 2*kk + 1];
        Wn[r][0]=(v2f){a.x,a.y}; Wn[r][1]=(v2f){a.z,a.w};
        Wn[r][2]=(v2f){c.x,c.y}; Wn[r][3]=(v2f){c.z,c.w};
        a = Whh4[(0*HD+row)*32 + 2*kk]; c = Whh4[(0*HD+row)*32 + 2*kk + 1];
        Whr[r][0]=(v2f){a.x,a.y}; Whr[r][1]=(v2f){a.z,a.w};
        Whr[r][2]=(v2f){c.x,c.y}; Whr[r][3]=(v2f){c.z,c.w};
        a = Whh4[(1*HD+row)*32 + 2*kk]; c = Whh4[(1*HD+row)*32 + 2*kk + 1];
        Whz[r][0]=(v2f){a.x,a.y}; Whz[r][1]=(v2f){a.z,a.w};
        Whz[r][2]=(v2f){c.x,c.y}; Whz[r][3]=(v2f){c.z,c.w};
        a = Whh4[(2*HD+row)*32 + 2*kk]; c = Whh4[(2*HD+row)*32 + 2*kk + 1];
        Whn[r][0]=(v2f){a.x,a.y}; Whn[r][1]=(v2f){a.z,a.w};
        Whn[r][2]=(v2f){c.x,c.y}; Whn[r][3]=(v2f){c.z,c.w};
        a = Wih4[(0*HD+row)*16 + kk];
        Wir[r][0]=(v2f){a.x,a.y}; Wir[r][1]=(v2f){a.z,a.w};
        a = Wih4[(1*HD+row)*16 + kk];
        Wiz[r][0]=(v2f){a.x,a.y}; Wiz[r][1]=(v2f){a.z,a.w};
        a = Wih4[(2*HD+row)*16 + kk];
        Win[r][0]=(v2f){a.x,a.y}; Win[r][1]=(v2f){a.z,a.w};
    }
    #pragma unroll
    for (int r = 0; r < 2; ++r) {
        const int row = 2*g + r;
        float4 a = Wo4[row*32 + 2*kk], c = Wo4[row*32 + 2*kk + 1];
        Wo[r][0]=(v2f){a.x,a.y}; Wo[r][1]=(v2f){a.z,a.w};
        Wo[r][2]=(v2f){c.x,c.y}; Wo[r][3]=(v2f){c.z,c.w};
    }
    // Pin: Wn in VGPRs (hot), the rest in AGPRs
    #pragma unroll
    for (int r = 0; r < 4; ++r) {
        #pragma unroll
        for (int i = 0; i < 4; ++i) {
            asm volatile("" : "+v"(Wn[r][i]));
            asm volatile("" : "+a"(Whr[r][i]));
            asm volatile("" : "+a"(Whz[r][i]));
            asm volatile("" : "+a"(Whn[r][i]));
        }
        #pragma unroll
        for (int i = 0; i < 2; ++i) {
            asm volatile("" : "+a"(Wir[r][i]));
            asm volatile("" : "+a"(Wiz[r][i]));
            asm volatile("" : "+a"(Win[r][i]));
        }
    }
    #pragma unroll
    for (int i = 0; i < 4; ++i) {
        asm volatile("" : "+a"(Wo[0][i]));
        asm volatile("" : "+a"(Wo[1][i]));
    }

    // per-lane biases for the row this lane owns after regroup
    const int rl = 4*g + rsel;
    const float bn  = b_node[rl];
    const float br  = b_ih[0*HD + rl] + b_hh[0*HD + rl];
    const float bz  = b_ih[1*HD + rl] + b_hh[1*HD + rl];
    const float bin = b_ih[2*HD + rl];
    const float bhn = b_hh[2*HD + rl];
    const float bo  = b_out[2*g + (kk & 1)];

    // ---- LDS init ----
    if (t < HSZ) sh_h[t] = 0.0f;                       // h0 = 0 (incl. pads)
    if (t < DIN) sh_po[t] = b_out[t];                  // prev_out(h0) = b_out
    if (t < DIN) sh_x[0][t] = x[(size_t)b * TSTEP * DIN + t];
    __syncthreads();

    const int soff = 12 * kk;   // this lane's swizzled slice base (floats)

    // 4-row partial dot over a swizzled 128-float LDS vector (thread k-slice)
    auto dotWn = [&](const float* buf, float (&acc)[4]) {
        const float4* p = (const float4*)(buf + soff);
        float4 a = p[0], c = p[1];
        v2f x0={a.x,a.y}, x1={a.z,a.w}, x2={c.x,c.y}, x3={c.z,c.w};
        #pragma unroll
        for (int r = 0; r < 4; ++r) {
            v2f s = Wn[r][0]*x0;
            s = Wn[r][1]*x1 + s; s = Wn[r][2]*x2 + s; s = Wn[r][3]*x3 + s;
            acc[r] = s.x + s.y;
        }
    };
    // reduce 4 row-partials over 16 lanes; lanes 12..15 get row 4g+rsel's total
    auto reduce4 = [&](const float (&acc)[4]) -> float {
        float s0 = qp3333(scan16(acc[0]));
        float s1 = qp3333(scan16(acc[1]));
        float s2 = qp3333(scan16(acc[2]));
        float s3 = qp3333(scan16(acc[3]));
        float lo = (rsel & 1) ? s1 : s0;
        float hi = (rsel & 1) ? s3 : s2;
        return (rsel & 2) ? hi : lo;
    };

    float hj = 0.0f;                  // owner lanes: h[4g+rsel]
    float tp_prev = tp[0] - 0.01f;    // dts[0] = 0.01

    #pragma unroll 1
    for (int s = 0; s < TSTEP; ++s) {
        const float tpv   = tp[s];
        const int   m_cur = samp_mask[s];
        const float dt    = tpv - tp_prev;
        tp_prev = tpv;

        // prefetch x row for step s+1 (consumed pre-B4)
        const int sn = (s + 1 < TSTEP) ? s + 1 : s;
        float xn = 0.0f;
        if (t < DIN) xn = x[((size_t)b * TSTEP + sn) * DIN + t];

        float acc[4];

        // ---- RK4 on dh/dt = tanh(Wn h + bn) ----
        dotWn(sh_h, acc);
        float k1 = fast_tanh(reduce4(acc) + bn);
        if (own4) sh_t0[gsw + rsel] = fmaf(0.5f*dt, k1, hj);
        __syncthreads();                                   // B1

        dotWn(sh_t0, acc);
        float k2 = fast_tanh(reduce4(acc) + bn);
        if (own4) sh_t1[gsw + rsel] = fmaf(0.5f*dt, k2, hj);
        __syncthreads();                                   // B2

        dotWn(sh_t1, acc);
        float k3 = fast_tanh(reduce4(acc) + bn);
        if (own4) sh_t0[gsw + rsel] = fmaf(dt, k3, hj);
        __syncthreads();                                   // B3

        dotWn(sh_t0, acc);
        float k4 = fast_tanh(reduce4(acc) + bn);
        const float hode = fmaf(dt * (1.0f/6.0f),
                                (k1 + 2.0f*k2) + (2.0f*k3 + k4), hj);
        if (own4) sh_t1[gsw + rsel] = hode;                // t1 = h_ode vector
        if (t < DIN) sh_x[(s + 1) & 1][t] = xn;            // stage next input
        __syncthreads();                                   // B4

        // ---- GRU cell: hidden from t1 (h_ode); input = mask ? x_s : prev_out
        {
            const float4* ph = (const float4*)(sh_t1 + soff);
            float4 a = ph[0], c = ph[1];
            v2f h0={a.x,a.y}, h1={a.z,a.w}, h2={c.x,c.y}, h3={c.z,c.w};
            const float* insrc = m_cur ? sh_x[s & 1] : sh_po;
            float4 vi = *(const float4*)(insrc + 4*kk);
            v2f i0={vi.x,vi.y}, i1={vi.z,vi.w};

            float aR[4], aZ[4], aNh[4], aNi[4];
            #pragma unroll
            for (int r = 0; r < 4; ++r) {
                v2f sR = Whr[r][0]*h0;
                sR = Whr[r][1]*h1 + sR; sR = Whr[r][2]*h2 + sR; sR = Whr[r][3]*h3 + sR;
                sR = Wir[r][0]*i0 + sR; sR = Wir[r][1]*i1 + sR;
                aR[r] = sR.x + sR.y;
                v2f sZ = Whz[r][0]*h0;
                sZ = Whz[r][1]*h1 + sZ; sZ = Whz[r][2]*h2 + sZ; sZ = Whz[r][3]*h3 + sZ;
                sZ = Wiz[r][0]*i0 + sZ; sZ = Wiz[r][1]*i1 + sZ;
                aZ[r] = sZ.x + sZ.y;
                v2f sH = Whn[r][0]*h0;
                sH = Whn[r][1]*h1 + sH; sH = Whn[r][2]*h2 + sH; sH = Whn[r][3]*h3 + sH;
                aNh[r] = sH.x + sH.y;
                v2f sI = Win[r][0]*i0; sI = Win[r][1]*i1 + sI;
                aNi[r] = sI.x + sI.y;
            }
            float R  = reduce4(aR);
            float Z  = reduce4(aZ);
            float Nh = reduce4(aNh);
            float Ni = reduce4(aNi);

            float rr = fast_sigmoid(R + br);
            float zz = fast_sigmoid(Z + bz);
            float nn = fast_tanh(fmaf(rr, Nh + bhn, Ni + bin));
            float hnew = fmaf(zz, hode - nn, nn);          // (1-z)n + z*h_ode
            hj = hnew;
            if (own4) sh_h[gsw + rsel] = hnew;
        }
        __syncthreads();                                   // B5

        // ---- out_t = h_new @ W_out^T + b_out (rows 2g, 2g+1 per group) ----
        {
            const float4* ph = (const float4*)(sh_h + soff);
            float4 a = ph[0], c = ph[1];
            v2f x0={a.x,a.y}, x1={a.z,a.w}, x2={c.x,c.y}, x3={c.z,c.w};
            float o01[2];
            #pragma unroll
            for (int r = 0; r < 2; ++r) {
                v2f so = Wo[r][0]*x0;
                so = Wo[r][1]*x1 + so; so = Wo[r][2]*x2 + so; so = Wo[r][3]*x3 + so;
                o01[r] = so.x + so.y;
            }
            float so0 = qp3333(scan16(o01[0]));
            float so1 = qp3333(scan16(o01[1]));
            float o = ((kk & 1) ? so1 : so0) + bo;
            if (kk >= 14) {                    // lanes 14,15 -> rows 2g, 2g+1
                const int col = 2*g + (kk & 1);
                sh_po[col] = o;
                out[((size_t)b * TSTEP + s) * DIN + col] = o;
            }
        }
        __syncthreads();                                   // B6
    }
}

extern "C" void kernel_launch(void* const* d_in, const int* in_sizes, int n_in,
                              void* d_out, int out_size, void* d_ws, size_t ws_size,
                              hipStream_t stream) {
    (void)in_sizes; (void)n_in; (void)d_ws; (void)ws_size; (void)out_size;
    const float* x      = (const float*)d_in[0];
    const float* tp     = (const float*)d_in[1];
    const int*   mask   = (const int*)  d_in[2];
    const float* W_ih   = (const float*)d_in[3];
    const float* W_hh   = (const float*)d_in[4];
    const float* b_ih   = (const float*)d_in[5];
    const float* b_hh   = (const float*)d_in[6];
    const float* W_node = (const float*)d_in[7];
    const float* b_node = (const float*)d_in[8];
    const float* W_out  = (const float*)d_in[9];
    const float* b_out  = (const float*)d_in[10];
    float* outp = (float*)d_out;

    gruode_kernel<<<NB, TB, 0, stream>>>(x, tp, mask, W_ih, W_hh, b_ih, b_hh,
                                         W_node, b_node, W_out, b_out, outp);
}